// Round 1
// baseline (236.392 us; speedup 1.0000x reference)
//
#include <hip/hip_runtime.h>
#include <hip/hip_bf16.h>

// Problem constants (from reference): N samples, J genes, P covariates.
constexpr int N_SAMPLES = 512;
constexpr int J_GENES   = 20000;
constexpr int P_COV     = 8;
constexpr int DIM       = J_GENES - 1;   // pivot=True drops last logit column
constexpr int BLOCK     = 256;

// ---------------------------------------------------------------------------
// Prep: per-gene quantities that are reused across all 512 rows.
//   disp = softplus(phi);  r = 1/disp;  store r, log(r), lgamma(r).
// Also zeroes d_out (harness poisons it with 0xAA before every launch).
// If rw==nullptr (ws too small fallback) only the out-zeroing runs.
// ---------------------------------------------------------------------------
__global__ void prep_kernel(const float* __restrict__ phi,
                            float* __restrict__ rw,
                            float* __restrict__ logrw,
                            float* __restrict__ lgrw,
                            float* __restrict__ out) {
    int j = blockIdx.x * blockDim.x + threadIdx.x;
    if (j == 0) out[0] = 0.0f;
    if (rw != nullptr && j < J_GENES) {
        float ph = phi[j];
        // stable softplus
        float sp = (ph > 20.0f) ? ph : log1pf(expf(ph));
        float r  = 1.0f / sp;
        rw[j]    = r;
        logrw[j] = -logf(sp);        // log(1/sp)
        lgrw[j]  = lgammaf(r);
    }
}

// ---------------------------------------------------------------------------
// Main: one block per sample row.
//   Pass 1: s = sum_j Y[n,j];  E = sum_j exp(logit[n,j])   (incl. pivot exp(0))
//   Pass 2: sum_j NB log-pmf, using log(mean)=log(s)+logit-lse.
// ---------------------------------------------------------------------------
__device__ inline float wave_reduce_sum(float v) {
#pragma unroll
    for (int off = 32; off > 0; off >>= 1)
        v += __shfl_down(v, off, 64);
    return v;
}

template <bool PREP>
__global__ __launch_bounds__(BLOCK) void nb_main(
    const float* __restrict__ mu,   const float* __restrict__ beta,
    const float* __restrict__ phi,  const float* __restrict__ X,
    const float* __restrict__ Y,
    const float* __restrict__ rw,   const float* __restrict__ logrw,
    const float* __restrict__ lgrw, float* __restrict__ out) {

    const int n = blockIdx.x;
    const int t = threadIdx.x;

    __shared__ float red[4];
    __shared__ float sh_s, sh_lse, sh_logs;

    // X row (8 floats) into registers; L1-served, every thread reads same line.
    float x[P_COV];
#pragma unroll
    for (int p = 0; p < P_COV; ++p) x[p] = X[n * P_COV + p];

    const float* yrow = Y + (size_t)n * J_GENES;

    // ---- pass 1: row total count s and softmax denominator ----
    float s_acc = 0.0f, e_acc = 0.0f;
    for (int j = t; j < J_GENES; j += BLOCK) {
        float logit = 0.0f;
        if (j < DIM) {
            logit = mu[j];
#pragma unroll
            for (int p = 0; p < P_COV; ++p)
                logit = fmaf(x[p], beta[p * DIM + j], logit);
        }
        s_acc += yrow[j];
        e_acc += expf(logit);
    }

    // block-reduce s
    float v = wave_reduce_sum(s_acc);
    if ((t & 63) == 0) red[t >> 6] = v;
    __syncthreads();
    if (t == 0) {
        float s_tot = red[0] + red[1] + red[2] + red[3];
        sh_s = s_tot;
        sh_logs = logf(s_tot);
    }
    __syncthreads();
    // block-reduce E
    v = wave_reduce_sum(e_acc);
    if ((t & 63) == 0) red[t >> 6] = v;
    __syncthreads();
    if (t == 0) sh_lse = logf(red[0] + red[1] + red[2] + red[3]);
    __syncthreads();

    const float s    = sh_s;
    const float logs = sh_logs;
    const float lse  = sh_lse;

    // ---- pass 2: NB log-likelihood ----
    float acc = 0.0f;
    for (int j = t; j < J_GENES; j += BLOCK) {
        float logit = 0.0f;
        if (j < DIM) {
            logit = mu[j];
#pragma unroll
            for (int p = 0; p < P_COV; ++p)
                logit = fmaf(x[p], beta[p * DIM + j], logit);
        }
        float r, logr_j, lgr_j;
        if (PREP) {
            r      = rw[j];
            logr_j = logrw[j];
            lgr_j  = lgrw[j];
        } else {
            float ph = phi[j];
            float sp = (ph > 20.0f) ? ph : log1pf(expf(ph));
            r      = 1.0f / sp;
            logr_j = -logf(sp);
            lgr_j  = lgammaf(r);
        }
        float y    = yrow[j];
        float lp   = logit - lse;          // log(pi)
        float mean = s * expf(lp);
        float lrm  = logf(r + mean);       // log(r + mean)
        // lgamma(y+r) - lgamma(r) - lgamma(y+1) + r*(log r - lrm) + y*(log mean - lrm)
        float term = lgammaf(y + r) - lgr_j - lgammaf(y + 1.0f)
                   + r * (logr_j - lrm)
                   + y * ((logs + lp) - lrm);
        acc += term;
    }

    v = wave_reduce_sum(acc);
    if ((t & 63) == 0) red[t >> 6] = v;
    __syncthreads();
    if (t == 0)
        atomicAdd(out, red[0] + red[1] + red[2] + red[3]);
}

extern "C" void kernel_launch(void* const* d_in, const int* in_sizes, int n_in,
                              void* d_out, int out_size, void* d_ws, size_t ws_size,
                              hipStream_t stream) {
    const float* mu   = (const float*)d_in[0];  // [DIM]
    const float* beta = (const float*)d_in[1];  // [P*DIM]
    const float* phi  = (const float*)d_in[2];  // [J]
    const float* X    = (const float*)d_in[3];  // [N,P]
    const float* Y    = (const float*)d_in[4];  // [N,J]
    float* out = (float*)d_out;

    const size_t need = (size_t)3 * J_GENES * sizeof(float);
    const bool use_prep = (ws_size >= need);
    float* rw    = (float*)d_ws;
    float* logrw = rw + J_GENES;
    float* lgrw  = rw + 2 * J_GENES;

    if (use_prep) {
        prep_kernel<<<(J_GENES + BLOCK - 1) / BLOCK, BLOCK, 0, stream>>>(
            phi, rw, logrw, lgrw, out);
        nb_main<true><<<N_SAMPLES, BLOCK, 0, stream>>>(
            mu, beta, phi, X, Y, rw, logrw, lgrw, out);
    } else {
        prep_kernel<<<1, 1, 0, stream>>>(phi, nullptr, nullptr, nullptr, out);
        nb_main<false><<<N_SAMPLES, BLOCK, 0, stream>>>(
            mu, beta, phi, X, Y, nullptr, nullptr, nullptr, out);
    }
}

// Round 2
// 149.875 us; speedup vs baseline: 1.5773x; 1.5773x over previous
//
#include <hip/hip_runtime.h>
#include <hip/hip_bf16.h>

// Problem constants (from reference)
constexpr int N_SAMPLES = 512;
constexpr int J_GENES   = 20000;
constexpr int P_COV     = 8;
constexpr int DIM       = J_GENES - 1;   // pivot=True: last logit column is 0
constexpr int BLOCK     = 256;
constexpr int CHUNK     = 1024;          // genes per block (256 thr x float4)
constexpr int CPR       = (J_GENES + CHUNK - 1) / CHUNK;   // 20 chunks/row
constexpr int TABLE_N   = 1024;          // lgamma(y+1) table, y in [0,1000]

// ---------------------------------------------------------------------------
// ws layout (floats):
//   rw      [J]       r = 1/softplus(phi)
//   logrw   [J]       log(r)
//   lgrw    [J]       lgamma(r)
//   muP     [J]       mu padded with 0 at j=DIM  (pivot logit = 0 falls out)
//   betaP   [P*J]     beta repacked [p][J], padded, float4-alignable
//   lgyt    [1024]    lgamma(k+1) table
//   sAcc    [512]     per-row sum(Y)
//   eAcc    [512]     per-row sum(exp(logit))
//   part    [512*20]  per-block loglik partials
constexpr size_t WS_RW    = 0;
constexpr size_t WS_LOGRW = WS_RW    + J_GENES;
constexpr size_t WS_LGRW  = WS_LOGRW + J_GENES;
constexpr size_t WS_MUP   = WS_LGRW  + J_GENES;
constexpr size_t WS_BETAP = WS_MUP   + J_GENES;
constexpr size_t WS_LGYT  = WS_BETAP + (size_t)P_COV * J_GENES;
constexpr size_t WS_SACC  = WS_LGYT  + TABLE_N;
constexpr size_t WS_EACC  = WS_SACC  + N_SAMPLES;
constexpr size_t WS_PART  = WS_EACC  + N_SAMPLES;
constexpr size_t WS_TOTAL = WS_PART  + (size_t)N_SAMPLES * CPR;   // floats

__device__ inline float wave_reduce_sum(float v) {
#pragma unroll
    for (int off = 32; off > 0; off >>= 1)
        v += __shfl_down(v, off, 64);
    return v;
}

// Stirling lgamma for z > 0 (z >= ~0.2 here). ~1e-6 accuracy, way inside the
// 2% absmax threshold. One native log (two for z<8, which is <1% of lanes).
__device__ inline float lgamma_pos(float z) {
    float corr = 0.0f;
    if (z < 8.0f) {
        float p = z;
        p *= (z + 1.0f); p *= (z + 2.0f); p *= (z + 3.0f);
        p *= (z + 4.0f); p *= (z + 5.0f); p *= (z + 6.0f); p *= (z + 7.0f);
        corr = -__logf(p);
        z += 8.0f;
    }
    float lz  = __logf(z);
    float rz  = __builtin_amdgcn_rcpf(z);
    float rz2 = rz * rz;
    // 1/(12z) - 1/(360 z^3) + 1/(1260 z^5)
    float ser = rz * fmaf(rz2, fmaf(rz2, 7.9365079365e-4f, -2.7777777778e-3f),
                          8.3333333333e-2f);
    return fmaf(z - 0.5f, lz, 0.91893853320467274f - z + ser + corr);
}

// ---------------------------------------------------------------------------
__global__ __launch_bounds__(BLOCK) void prep_kernel(
    const float* __restrict__ mu, const float* __restrict__ beta,
    const float* __restrict__ phi, float* __restrict__ ws) {
    int j = blockIdx.x * blockDim.x + threadIdx.x;
    if (j < N_SAMPLES) { ws[WS_SACC + j] = 0.0f; ws[WS_EACC + j] = 0.0f; }
    if (j < TABLE_N)   ws[WS_LGYT + j] = lgammaf((float)j + 1.0f);
    if (j < J_GENES) {
        float ph = phi[j];
        float sp = (ph > 20.0f) ? ph : log1pf(__expf(ph));  // softplus
        float r  = 1.0f / sp;
        ws[WS_RW    + j] = r;
        ws[WS_LOGRW + j] = -__logf(sp);
        ws[WS_LGRW  + j] = lgammaf(r);
        ws[WS_MUP   + j] = (j < DIM) ? mu[j] : 0.0f;
#pragma unroll
        for (int p = 0; p < P_COV; ++p)
            ws[WS_BETAP + (size_t)p * J_GENES + j] =
                (j < DIM) ? beta[p * DIM + j] : 0.0f;
    }
}

// ---------------------------------------------------------------------------
// Pass 1: per-row total count s and softmax denominator E (padded logits
// include the pivot column automatically: logit[DIM] = 0).
__global__ __launch_bounds__(BLOCK) void pass1_kernel(
    const float* __restrict__ X, const float* __restrict__ Y,
    const float* __restrict__ ws_c, float* __restrict__ ws) {
    const int n = blockIdx.y;
    const int t = threadIdx.x;
    const int j = blockIdx.x * CHUNK + t * 4;

    float x[P_COV];
#pragma unroll
    for (int p = 0; p < P_COV; ++p) x[p] = X[n * P_COV + p];

    float s_acc = 0.0f, e_acc = 0.0f;
    if (j < J_GENES) {
        float4 y4 = *(const float4*)(Y + (size_t)n * J_GENES + j);
        float4 lg = *(const float4*)(ws_c + WS_MUP + j);
#pragma unroll
        for (int p = 0; p < P_COV; ++p) {
            float4 b = *(const float4*)(ws_c + WS_BETAP + (size_t)p * J_GENES + j);
            lg.x = fmaf(x[p], b.x, lg.x);
            lg.y = fmaf(x[p], b.y, lg.y);
            lg.z = fmaf(x[p], b.z, lg.z);
            lg.w = fmaf(x[p], b.w, lg.w);
        }
        s_acc = (y4.x + y4.y) + (y4.z + y4.w);
        e_acc = (__expf(lg.x) + __expf(lg.y)) + (__expf(lg.z) + __expf(lg.w));
    }

    float vs = wave_reduce_sum(s_acc);
    float ve = wave_reduce_sum(e_acc);
    __shared__ float rs[4], re[4];
    if ((t & 63) == 0) { rs[t >> 6] = vs; re[t >> 6] = ve; }
    __syncthreads();
    if (t == 0) {
        atomicAdd(&ws[WS_SACC + n], (rs[0] + rs[1]) + (rs[2] + rs[3]));
        atomicAdd(&ws[WS_EACC + n], (re[0] + re[1]) + (re[2] + re[3]));
    }
}

// ---------------------------------------------------------------------------
// Pass 2: NB log-likelihood partial per block.
__device__ inline float nb_term(float y, float logit, float r, float logr,
                                float lgr, float s, float logs, float lse,
                                const float* __restrict__ tbl) {
    float lp   = logit - lse;            // log(pi)
    float mean = s * __expf(lp);
    float lrm  = __logf(r + mean);       // log(r + mean)
    int   yi   = (int)(y + 0.5f);
    float lgy1 = (yi >= 0 && yi < TABLE_N) ? tbl[yi] : lgamma_pos(y + 1.0f);
    float lgyr = lgamma_pos(y + r);
    // lgamma(y+r) - lgamma(r) - lgamma(y+1) + r*(logr - lrm) + y*(logmean - lrm)
    return lgyr - lgr - lgy1 + fmaf(r, logr - lrm, y * ((logs + lp) - lrm));
}

__global__ __launch_bounds__(BLOCK) void pass2_kernel(
    const float* __restrict__ X, const float* __restrict__ Y,
    const float* __restrict__ ws_c, float* __restrict__ ws) {
    const int n = blockIdx.y;
    const int t = threadIdx.x;
    const int j = blockIdx.x * CHUNK + t * 4;

    __shared__ __align__(16) float tbl[TABLE_N];
    __shared__ float shv[3];   // s, log(s), lse
    *(float4*)&tbl[t * 4] = *(const float4*)(ws_c + WS_LGYT + t * 4);
    if (t == 0) {
        float s = ws_c[WS_SACC + n];
        float E = ws_c[WS_EACC + n];
        shv[0] = s; shv[1] = __logf(s); shv[2] = __logf(E);
    }
    __syncthreads();
    const float s = shv[0], logs = shv[1], lse = shv[2];

    float x[P_COV];
#pragma unroll
    for (int p = 0; p < P_COV; ++p) x[p] = X[n * P_COV + p];

    float acc = 0.0f;
    if (j < J_GENES) {
        float4 y4  = *(const float4*)(Y + (size_t)n * J_GENES + j);
        float4 lg  = *(const float4*)(ws_c + WS_MUP + j);
#pragma unroll
        for (int p = 0; p < P_COV; ++p) {
            float4 b = *(const float4*)(ws_c + WS_BETAP + (size_t)p * J_GENES + j);
            lg.x = fmaf(x[p], b.x, lg.x);
            lg.y = fmaf(x[p], b.y, lg.y);
            lg.z = fmaf(x[p], b.z, lg.z);
            lg.w = fmaf(x[p], b.w, lg.w);
        }
        float4 r4  = *(const float4*)(ws_c + WS_RW    + j);
        float4 lr4 = *(const float4*)(ws_c + WS_LOGRW + j);
        float4 lg4 = *(const float4*)(ws_c + WS_LGRW  + j);
        acc  = nb_term(y4.x, lg.x, r4.x, lr4.x, lg4.x, s, logs, lse, tbl);
        acc += nb_term(y4.y, lg.y, r4.y, lr4.y, lg4.y, s, logs, lse, tbl);
        acc += nb_term(y4.z, lg.z, r4.z, lr4.z, lg4.z, s, logs, lse, tbl);
        acc += nb_term(y4.w, lg.w, r4.w, lr4.w, lg4.w, s, logs, lse, tbl);
    }

    float v = wave_reduce_sum(acc);
    __shared__ float red[4];
    if ((t & 63) == 0) red[t >> 6] = v;
    __syncthreads();
    if (t == 0)
        ws[WS_PART + (size_t)n * CPR + blockIdx.x] =
            (red[0] + red[1]) + (red[2] + red[3]);
}

// ---------------------------------------------------------------------------
__global__ __launch_bounds__(BLOCK) void final_kernel(
    const float* __restrict__ ws_c, float* __restrict__ out) {
    const int t = threadIdx.x;
    float acc = 0.0f;
    for (int i = t; i < N_SAMPLES * CPR; i += BLOCK)
        acc += ws_c[WS_PART + i];
    float v = wave_reduce_sum(acc);
    __shared__ float red[4];
    if ((t & 63) == 0) red[t >> 6] = v;
    __syncthreads();
    if (t == 0) out[0] = (red[0] + red[1]) + (red[2] + red[3]);
}

// ---------------------------------------------------------------------------
// Fallback (ws too small): round-1 monolithic kernel, known-correct.
__global__ __launch_bounds__(BLOCK) void nb_mono(
    const float* __restrict__ mu, const float* __restrict__ beta,
    const float* __restrict__ phi, const float* __restrict__ X,
    const float* __restrict__ Y, float* __restrict__ out) {
    const int n = blockIdx.x;
    const int t = threadIdx.x;
    __shared__ float red[4];
    __shared__ float sh_s, sh_lse, sh_logs;
    float x[P_COV];
#pragma unroll
    for (int p = 0; p < P_COV; ++p) x[p] = X[n * P_COV + p];
    const float* yrow = Y + (size_t)n * J_GENES;
    float s_acc = 0.0f, e_acc = 0.0f;
    for (int j = t; j < J_GENES; j += BLOCK) {
        float logit = 0.0f;
        if (j < DIM) {
            logit = mu[j];
#pragma unroll
            for (int p = 0; p < P_COV; ++p)
                logit = fmaf(x[p], beta[p * DIM + j], logit);
        }
        s_acc += yrow[j];
        e_acc += __expf(logit);
    }
    float v = wave_reduce_sum(s_acc);
    if ((t & 63) == 0) red[t >> 6] = v;
    __syncthreads();
    if (t == 0) { float st = red[0]+red[1]+red[2]+red[3]; sh_s = st; sh_logs = __logf(st); }
    __syncthreads();
    v = wave_reduce_sum(e_acc);
    if ((t & 63) == 0) red[t >> 6] = v;
    __syncthreads();
    if (t == 0) sh_lse = __logf(red[0]+red[1]+red[2]+red[3]);
    __syncthreads();
    const float s = sh_s, logs = sh_logs, lse = sh_lse;
    float acc = 0.0f;
    for (int j = t; j < J_GENES; j += BLOCK) {
        float logit = 0.0f;
        if (j < DIM) {
            logit = mu[j];
#pragma unroll
            for (int p = 0; p < P_COV; ++p)
                logit = fmaf(x[p], beta[p * DIM + j], logit);
        }
        float ph = phi[j];
        float sp = (ph > 20.0f) ? ph : log1pf(__expf(ph));
        float r  = 1.0f / sp;
        float y  = yrow[j];
        float lp = logit - lse;
        float mean = s * __expf(lp);
        float lrm  = __logf(r + mean);
        acc += lgamma_pos(y + r) - lgamma_pos(r) - lgamma_pos(y + 1.0f)
             + fmaf(r, -__logf(sp) - lrm, y * ((logs + lp) - lrm));
    }
    v = wave_reduce_sum(acc);
    if ((t & 63) == 0) red[t >> 6] = v;
    __syncthreads();
    if (t == 0) atomicAdd(out, (red[0]+red[1])+(red[2]+red[3]));
}

__global__ void zero_out_kernel(float* __restrict__ out) { out[0] = 0.0f; }

// ---------------------------------------------------------------------------
extern "C" void kernel_launch(void* const* d_in, const int* in_sizes, int n_in,
                              void* d_out, int out_size, void* d_ws, size_t ws_size,
                              hipStream_t stream) {
    const float* mu   = (const float*)d_in[0];  // [DIM]
    const float* beta = (const float*)d_in[1];  // [P*DIM]
    const float* phi  = (const float*)d_in[2];  // [J]
    const float* X    = (const float*)d_in[3];  // [N,P]
    const float* Y    = (const float*)d_in[4];  // [N,J]
    float* out = (float*)d_out;
    float* ws  = (float*)d_ws;

    if (ws_size >= WS_TOTAL * sizeof(float)) {
        dim3 grid(CPR, N_SAMPLES);
        prep_kernel<<<(J_GENES + BLOCK - 1) / BLOCK, BLOCK, 0, stream>>>(
            mu, beta, phi, ws);
        pass1_kernel<<<grid, BLOCK, 0, stream>>>(X, Y, ws, ws);
        pass2_kernel<<<grid, BLOCK, 0, stream>>>(X, Y, ws, ws);
        final_kernel<<<1, BLOCK, 0, stream>>>(ws, out);
    } else {
        zero_out_kernel<<<1, 1, 0, stream>>>(out);
        nb_mono<<<N_SAMPLES, BLOCK, 0, stream>>>(mu, beta, phi, X, Y, out);
    }
}